// Round 12
// baseline (283.602 us; speedup 1.0000x reference)
//
#include <hip/hip_runtime.h>
#include <hip/hip_bf16.h>

#define EPS 1e-5f

typedef __attribute__((ext_vector_type(8))) short bf16x8;
typedef __attribute__((ext_vector_type(4))) float f32x4;

// ---------------- workspace layout (bytes) ----------------
static constexpr size_t OFF_FT    = 0;             // fT[b][c][n] f32 (1 MB)
static constexpr size_t OFF_W1T   = 1048576;       // W1T[c][o512] f32 (512 KB)
static constexpr size_t OFF_W2B   = 1572864;       // W2 bf16 [128][256] (64 KB)
static constexpr size_t OFF_W3B   = 1638400;       // W3 bf16 [64][128] (16 KB)
static constexpr size_t OFF_S1    = 1654784;       // s1[256]
static constexpr size_t OFF_T1    = 1655808;       // t1[256]
static constexpr size_t OFF_ST2   = 1660928;       // gS2[8][128],gQ2[8][128],gS3[8][64],gQ3[8][64],counter
static constexpr size_t OFF_ABT   = 1703936;       // abT[b][n][o512] f32 (2 MB)
static constexpr size_t OFF_H2T   = 4194304;       // h2T bf16 (64 MB); k1 partials overlap (dead before k2)
static constexpr size_t OFF_P1    = OFF_H2T;       // part float2[16][512]
static constexpr size_t OFF_H3T   = 71303168;      // h3T bf16 (32 MB)

static __device__ inline float bfu2f(unsigned int u16) {
    return __uint_as_float(u16 << 16);
}
static __device__ inline unsigned short f2bfu(float f) {
    unsigned int u = __float_as_uint(f);
    unsigned int r = u + 0x7fffu + ((u >> 16) & 1u);   // RNE
    return (unsigned short)(r >> 16);
}
static __device__ inline unsigned int pkbf(float lo, float hi) {
    __hip_bfloat162 p = __float22bfloat162_rn(make_float2(lo, hi));   // v_cvt_pk_bf16_f32
    return *reinterpret_cast<unsigned int*>(&p);
}

// relu(bn(fv)) for 4 f32 lanes -> 4 packed bf16
static __device__ __forceinline__ uint2 bnpk4(float4 fv, const float* aa, const float* ss, int c) {
    float4 a4 = *(const float4*)(aa + c);
    float4 s4 = *(const float4*)(ss + c);
    float r0 = fmaxf(fmaf(fv.x, s4.x, a4.x), 0.f);
    float r1 = fmaxf(fmaf(fv.y, s4.y, a4.y), 0.f);
    float r2 = fmaxf(fmaf(fv.z, s4.z, a4.z), 0.f);
    float r3 = fmaxf(fmaf(fv.w, s4.w, a4.w), 0.f);
    return make_uint2(pkbf(r0, r1), pkbf(r2, r3));
}
// same but input = 4 bf16 packed in uint2
static __device__ __forceinline__ uint2 bn2pk4(uint2 v, const float* ss, const float* tt, int c) {
    float4 s4 = *(const float4*)(ss + c);
    float4 t4 = *(const float4*)(tt + c);
    float r0 = fmaxf(fmaf(bfu2f(v.x & 0xffffu), s4.x, t4.x), 0.f);
    float r1 = fmaxf(fmaf(bfu2f(v.x >> 16),     s4.y, t4.y), 0.f);
    float r2 = fmaxf(fmaf(bfu2f(v.y & 0xffffu), s4.z, t4.z), 0.f);
    float r3 = fmaxf(fmaf(bfu2f(v.y >> 16),     s4.w, t4.w), 0.f);
    return make_uint2(pkbf(r0, r1), pkbf(r2, r3));
}

// ---------------- K0KT: pair-mean transpose + weight prep + stats zeroing (800 blocks) ------
__global__ __launch_bounds__(256) void k0kt(const float* __restrict__ feats,
                                            const float* __restrict__ W1,
                                            const float* __restrict__ W2,
                                            const float* __restrict__ W3,
                                            float* __restrict__ fT, float* __restrict__ W1T,
                                            unsigned short* __restrict__ W2b,
                                            unsigned short* __restrict__ W3b,
                                            float* __restrict__ statsZero) {
    int bx = blockIdx.x, tid = threadIdx.x;
    if (bx < 128) {
        __shared__ float s[32][65];
        int b = bx >> 5, nt = (bx >> 2) & 7, ct = bx & 3;
        int n0 = nt * 32, c0 = ct * 64;
        const float* fb = feats + (size_t)b * 513 * 256;
        #pragma unroll
        for (int k = 0; k < 8; ++k) {
            int idx = tid + k * 256;
            int n = idx >> 6, c = idx & 63;
            const float* r = fb + (size_t)(1 + 2 * (n0 + n)) * 256 + c0 + c;
            s[n][c] = 0.5f * (r[0] + r[256]);
        }
        __syncthreads();
        #pragma unroll
        for (int k = 0; k < 8; ++k) {
            int idx = tid + k * 256;
            int c = idx >> 5, n = idx & 31;
            fT[((size_t)(b * 256) + c0 + c) * 256 + n0 + n] = s[n][c];
        }
    } else {
        if (bx == 128) {
            #pragma unroll
            for (int z = 0; z < 13; ++z) {
                int f = tid + z * 256;
                if (f < 3073) statsZero[f] = 0.f;   // gS2,gQ2,gS3,gQ3,counter
            }
        }
        int idx = (bx - 128) * 256 + tid;
        if (idx < 131072) {
            int c = idx >> 9, o = idx & 511;
            W1T[idx] = (o < 256) ? W1[(size_t)o * 512 + c] : W1[(size_t)(o - 256) * 512 + 256 + c];
        } else if (idx < 163840) {
            int j = idx - 131072;
            W2b[j] = f2bfu(W2[j]);
        } else if (idx < 172032) {
            int j = idx - 163840;
            W3b[j] = f2bfu(W3[j]);
        }
    }
}

// ---------------- K1: abT = W1T^T fT + BN1 partials; last block solves s1/t1 ----------------
__global__ __launch_bounds__(256) void k1_gemm(const float* __restrict__ W1T,
                                               const float* __restrict__ fT,
                                               float* __restrict__ abT,
                                               float2* __restrict__ part,
                                               const float* __restrict__ g1,
                                               const float* __restrict__ be1,
                                               float* __restrict__ s1,
                                               float* __restrict__ t1,
                                               unsigned int* __restrict__ counter) {
    __shared__ float sW[64][36];
    __shared__ float sF[64][68];
    int tid = threadIdx.x;
    int bx = blockIdx.x;
    int b = bx >> 2, n0 = (bx & 3) * 64;
    int o0 = blockIdx.y * 32;
    int og = tid >> 4, jq = tid & 15;
    float acc[2][4] = {};
    for (int c0 = 0; c0 < 256; c0 += 64) {
        #pragma unroll
        for (int k = 0; k < 8; ++k) {
            int idx = tid + k * 256;
            int c = idx >> 5, o = idx & 31;
            sW[c][o] = W1T[(size_t)(c0 + c) * 512 + o0 + o];
        }
        #pragma unroll
        for (int k = 0; k < 16; ++k) {
            int idx = tid + k * 256;
            int c = idx >> 6, n = idx & 63;
            sF[c][n] = fT[((size_t)(b * 256) + c0 + c) * 256 + n0 + n];
        }
        __syncthreads();
        #pragma unroll 8
        for (int c = 0; c < 64; ++c) {
            float4 rv = *(const float4*)&sF[c][jq * 4];
            float2 wv = *(const float2*)&sW[c][og * 2];
            float rr[4] = {rv.x, rv.y, rv.z, rv.w};
            #pragma unroll
            for (int w = 0; w < 4; ++w) {
                acc[0][w] = fmaf(wv.x, rr[w], acc[0][w]);
                acc[1][w] = fmaf(wv.y, rr[w], acc[1][w]);
            }
        }
        __syncthreads();
    }
    #pragma unroll
    for (int w = 0; w < 4; ++w) {
        int n = n0 + jq * 4 + w;
        *(float2*)&abT[((size_t)(b * 256) + n) * 512 + o0 + og * 2] =
            make_float2(acc[0][w], acc[1][w]);
    }
    #pragma unroll
    for (int m = 0; m < 2; ++m) {
        float s = 0.f, q = 0.f;
        #pragma unroll
        for (int w = 0; w < 4; ++w) { float v = acc[m][w]; s += v; q += v * v; }
        #pragma unroll
        for (int off = 8; off; off >>= 1) { s += __shfl_down(s, off); q += __shfl_down(q, off); }
        if (jq == 0) part[(size_t)bx * 512 + o0 + og * 2 + m] = make_float2(s, q);
    }
    // ticket: last block of 256 solves BN1 params
    __threadfence();
    __shared__ unsigned int lastFlag;
    if (tid == 0) lastFlag = (atomicAdd(counter, 1u) == 255u) ? 1u : 0u;
    __syncthreads();
    if (lastFlag) {
        int o = tid;   // 0..255
        float msum = 0.f, e2sum = 0.f;
        #pragma unroll
        for (int bb = 0; bb < 4; ++bb) {
            float Sa = 0.f, Qa = 0.f, Sb = 0.f, Qb = 0.f;
            #pragma unroll
            for (int nt = 0; nt < 4; ++nt) {
                float2 pa = part[(size_t)(bb * 4 + nt) * 512 + o];
                float2 pb = part[(size_t)(bb * 4 + nt) * 512 + 256 + o];
                Sa += pa.x; Qa += pa.y; Sb += pb.x; Qb += pb.y;
            }
            float ma = Sa * (1.f / 256.f), mb = Sb * (1.f / 256.f);
            msum += ma + mb;
            e2sum += Qa * (1.f / 256.f) + Qb * (1.f / 256.f) + 2.f * ma * mb;
        }
        float m = msum * 0.25f, e2 = e2sum * 0.25f;
        float var = e2 - m * m;
        float s = g1[o] * rsqrtf(var + EPS);
        s1[o] = s;
        t1[o] = be1[o] - m * s;
    }
}

// ---------------- K2: h2T = W2 @ relu(bn1(a_i + bp_j)) -- 128o x 256j tile -----------------
// grid (256 i, 4 b); 4 waves 2x2 (o-half x j-half); K=256, BK=32, LDS staging.
// 32 MFMA per barrier-region; acc in AGPRs; stats via sT column-read (AGPR-safe).
__global__ __launch_bounds__(256) void k2_mfma(const float* __restrict__ abT,
                                               const unsigned short* __restrict__ W2b,
                                               const float* __restrict__ s1,
                                               const float* __restrict__ t1,
                                               unsigned short* __restrict__ h2T,
                                               float* __restrict__ gS2,
                                               float* __restrict__ gQ2) {
    __shared__ __align__(16) char smem[39936];
    float* aaS = (float*)smem;                                    // [256]
    float* ssS = (float*)(smem + 1024);                           // [256]
    float* sS  = (float*)(smem + 2048);                           // [128]
    float* sQ  = (float*)(smem + 2560);                           // [128]
    unsigned short* sW = (unsigned short*)(smem + 3072);          // [128][40]  (10240 B)
    unsigned short* sB = (unsigned short*)(smem + 13312);         // [256][40]  (20480 B)
    unsigned short* sT = (unsigned short*)(smem + 3072);          // [256][72] epilogue union

    int tid = threadIdx.x;
    int i = blockIdx.x, b = blockIdx.y;

    {
        float av = abT[((size_t)(b * 256 + i)) * 512 + tid];
        float s = s1[tid];
        aaS[tid] = fmaf(av, s, t1[tid]);
        ssS[tid] = s;
    }
    if (tid < 128) { sS[tid] = 0.f; sQ[tid] = 0.f; }
    __syncthreads();

    int lane = tid & 63, wv = tid >> 6;
    int wr = wv >> 1, wc = wv & 1;          // o-half, j-half
    int lo = lane & 15, khi = lane >> 4;

    const float* bpRow = abT + ((size_t)(b * 256 + tid)) * 512 + 256;   // j-row = tid
    const unsigned short* wRow = W2b + (tid >> 1) * 256 + (tid & 1) * 16;

    f32x4 acc[4][8] = {};

    for (int c0 = 0; c0 < 256; c0 += 32) {
        // stage sW[o=tid>>1][c-chunk half]
        {
            uint4 v0 = *(const uint4*)(wRow + c0);
            uint4 v1 = *(const uint4*)(wRow + c0 + 8);
            uint4* dst = (uint4*)(sW + (tid >> 1) * 40 + (tid & 1) * 16);
            dst[0] = v0; dst[1] = v1;
        }
        // stage sB[j=tid][c-chunk] = relu(bn1) bf16 (full 32 c per thread)
        {
            float4 f0 = *(const float4*)(bpRow + c0);
            float4 f1 = *(const float4*)(bpRow + c0 + 4);
            float4 f2 = *(const float4*)(bpRow + c0 + 8);
            float4 f3 = *(const float4*)(bpRow + c0 + 12);
            float4 f4 = *(const float4*)(bpRow + c0 + 16);
            float4 f5 = *(const float4*)(bpRow + c0 + 20);
            float4 f6 = *(const float4*)(bpRow + c0 + 24);
            float4 f7 = *(const float4*)(bpRow + c0 + 28);
            uint2 p0 = bnpk4(f0, aaS, ssS, c0);
            uint2 p1 = bnpk4(f1, aaS, ssS, c0 + 4);
            uint2 p2 = bnpk4(f2, aaS, ssS, c0 + 8);
            uint2 p3 = bnpk4(f3, aaS, ssS, c0 + 12);
            uint2 p4 = bnpk4(f4, aaS, ssS, c0 + 16);
            uint2 p5 = bnpk4(f5, aaS, ssS, c0 + 20);
            uint2 p6 = bnpk4(f6, aaS, ssS, c0 + 24);
            uint2 p7 = bnpk4(f7, aaS, ssS, c0 + 28);
            uint4* dst = (uint4*)(sB + tid * 40);
            dst[0] = make_uint4(p0.x, p0.y, p1.x, p1.y);
            dst[1] = make_uint4(p2.x, p2.y, p3.x, p3.y);
            dst[2] = make_uint4(p4.x, p4.y, p5.x, p5.y);
            dst[3] = make_uint4(p6.x, p6.y, p7.x, p7.y);
        }
        __syncthreads();
        const unsigned short* aB = sW + (wr * 64 + lo) * 40 + khi * 8;
        const unsigned short* bB = sB + (wc * 128 + lo) * 40 + khi * 8;
        bf16x8 af[4], bfr[8];
        #pragma unroll
        for (int fm = 0; fm < 4; ++fm) af[fm] = *(const bf16x8*)(aB + fm * 16 * 40);
        #pragma unroll
        for (int fn = 0; fn < 8; ++fn) bfr[fn] = *(const bf16x8*)(bB + fn * 16 * 40);
        #pragma unroll
        for (int fm = 0; fm < 4; ++fm)
            #pragma unroll
            for (int fn = 0; fn < 8; ++fn)
                acc[fm][fn] = __builtin_amdgcn_mfma_f32_16x16x32_bf16(af[fm], bfr[fn], acc[fm][fn], 0, 0, 0);
        __syncthreads();
    }

    // epilogue: two o-half rounds through sT[256][72]; per-round col-read stats (AGPR-safe)
    #pragma unroll
    for (int rr = 0; rr < 2; ++rr) {
        __syncthreads();
        if (wr == rr) {
            #pragma unroll
            for (int fm = 0; fm < 4; ++fm)
                #pragma unroll
                for (int fn = 0; fn < 8; ++fn) {
                    int oq = fm * 16 + khi * 4;              // local o (0..63)
                    int j  = wc * 128 + fn * 16 + lo;        // 0..255
                    *(uint2*)(sT + j * 72 + oq) =
                        make_uint2(pkbf(acc[fm][fn][0], acc[fm][fn][1]),
                                   pkbf(acc[fm][fn][2], acc[fm][fn][3]));
                }
        }
        __syncthreads();
        // copy row tid (64 o-channels of this round) to global
        {
            size_t gbase = (((size_t)(b * 256 + i)) * 256 + tid) * 128 + rr * 64;
            #pragma unroll
            for (int e = 0; e < 8; ++e) {
                uint4 v = *(const uint4*)(sT + tid * 72 + e * 8);
                *(uint4*)(h2T + gbase + e * 8) = v;
            }
        }
        // BN2 block-stats: column-read of sT (bf16-rounded h2)
        {
            int o = tid & 63, p = tid >> 6;
            const unsigned short* col = sT + (p * 64) * 72 + o;
            float s = 0.f, q = 0.f;
            for (int j = 0; j < 64; ++j) {
                float v = bfu2f(col[j * 72]);
                s += v; q += v * v;
            }
            atomicAdd(&sS[rr * 64 + o], s);
            atomicAdd(&sQ[rr * 64 + o], q);
        }
    }
    __syncthreads();
    if (tid < 128) {
        int slot = (i & 7) * 128;
        atomicAdd(&gS2[slot + tid], sS[tid]);
        atomicAdd(&gQ2[slot + tid], sQ[tid]);
    }
}

// ---------------- K3: h3T = W3 @ relu(bn2(h2T)) -- inline bn2 params, AGPR-safe stats -------
// grid (256 i, 4 b); 4 waves 1x4; tile 64o x 256j; K=128, BK=32, LDS staging.
__global__ __launch_bounds__(256) void k3_mfma(const unsigned short* __restrict__ h2T,
                                               const unsigned short* __restrict__ W3b,
                                               const float* __restrict__ gS2,
                                               const float* __restrict__ gQ2,
                                               const float* __restrict__ g2,
                                               const float* __restrict__ be2,
                                               unsigned short* __restrict__ h3T,
                                               float* __restrict__ gS3,
                                               float* __restrict__ gQ3) {
    __shared__ __align__(16) char smem[39424];
    float* s2S = (float*)smem;                                    // [128]
    float* t2S = (float*)(smem + 512);                            // [128]
    unsigned short* sW3 = (unsigned short*)(smem + 1024);         // [64][136] full K
    unsigned short* sB  = (unsigned short*)(smem + 18432);        // [256][40] chunk
    float* sS = (float*)(smem + 38912);                           // [64]
    float* sQ = (float*)(smem + 39168);                           // [64]
    unsigned short* sT  = (unsigned short*)(smem + 1024);         // [256][72] epilogue overlap

    int tid = threadIdx.x;
    int i = blockIdx.x, b = blockIdx.y;
    if (tid < 128) {                       // inline BN2 param solve
        float su = 0.f, qu = 0.f;
        #pragma unroll
        for (int k = 0; k < 8; ++k) { su += gS2[k * 128 + tid]; qu += gQ2[k * 128 + tid]; }
        float mean = su * (1.f / 262144.f);
        float var = qu * (1.f / 262144.f) - mean * mean;
        float sc = g2[tid] * rsqrtf(var + EPS);
        s2S[tid] = sc;
        t2S[tid] = be2[tid] - mean * sc;
    }
    if (tid < 64) { sS[tid] = 0.f; sQ[tid] = 0.f; }
    {
        int o = tid >> 2, qd = tid & 3;
        #pragma unroll
        for (int e = 0; e < 4; ++e) {
            uint4 v = *(const uint4*)(W3b + o * 128 + qd * 32 + e * 8);
            *(uint4*)(sW3 + o * 136 + qd * 32 + e * 8) = v;
        }
    }
    __syncthreads();

    int lane = tid & 63, wv = tid >> 6;
    int lo = lane & 15, khi = lane >> 4;

    f32x4 acc[4][4] = {};
    const unsigned short* src = h2T + (((size_t)(b * 256 + i)) * 256 + tid) * 128;

    for (int c0 = 0; c0 < 128; c0 += 32) {
        #pragma unroll
        for (int e = 0; e < 4; ++e) {
            uint4 v = *(const uint4*)(src + c0 + e * 8);
            int c = c0 + e * 8;
            uint2 pa = bn2pk4(make_uint2(v.x, v.y), s2S, t2S, c);
            uint2 pb = bn2pk4(make_uint2(v.z, v.w), s2S, t2S, c + 4);
            *(uint4*)(sB + tid * 40 + e * 8) = make_uint4(pa.x, pa.y, pb.x, pb.y);
        }
        __syncthreads();
        bf16x8 af[4], bfr[4];
        #pragma unroll
        for (int fm = 0; fm < 4; ++fm)
            af[fm] = *(const bf16x8*)(sW3 + (fm * 16 + lo) * 136 + c0 + khi * 8);
        #pragma unroll
        for (int fn = 0; fn < 4; ++fn)
            bfr[fn] = *(const bf16x8*)(sB + (wv * 64 + fn * 16 + lo) * 40 + khi * 8);
        #pragma unroll
        for (int fm = 0; fm < 4; ++fm)
            #pragma unroll
            for (int fn = 0; fn < 4; ++fn)
                acc[fm][fn] = __builtin_amdgcn_mfma_f32_16x16x32_bf16(af[fm], bfr[fn], acc[fm][fn], 0, 0, 0);
        __syncthreads();
    }

    // epilogue: transpose to channel-last
    #pragma unroll
    for (int fm = 0; fm < 4; ++fm)
        #pragma unroll
        for (int fn = 0; fn < 4; ++fn) {
            int oq = fm * 16 + khi * 4;
            int j  = wv * 64 + fn * 16 + lo;
            *(uint2*)(sT + j * 72 + oq) =
                make_uint2(pkbf(acc[fm][fn][0], acc[fm][fn][1]),
                           pkbf(acc[fm][fn][2], acc[fm][fn][3]));
        }
    __syncthreads();
    {
        size_t gbase = (((size_t)(b * 256 + i)) * 256 + tid) * 64;
        #pragma unroll
        for (int e = 0; e < 8; ++e) {
            uint4 v = *(const uint4*)(sT + tid * 72 + e * 8);
            *(uint4*)(h3T + gbase + e * 8) = v;
        }
    }
    // BN3 block-stats: column-read of sT (bf16-rounded h3)
    {
        int o = tid & 63, p = tid >> 6;
        const unsigned short* col = sT + (p * 64) * 72 + o;
        float s = 0.f, q = 0.f;
        for (int j = 0; j < 64; ++j) {
            float v = bfu2f(col[j * 72]);
            s += v; q += v * v;
        }
        atomicAdd(&sS[o], s);
        atomicAdd(&sQ[o], q);
    }
    __syncthreads();
    if (tid < 64) {
        int slot = (i & 7) * 64;
        atomicAdd(&gS3[slot + tid], sS[tid]);
        atomicAdd(&gQ3[slot + tid], sQ[tid]);
    }
}

// ---------------- K4: out = W4 @ relu(bn3(h3T)) + b4, inline bn3 params ----------------
__global__ __launch_bounds__(256) void k4_final(const unsigned short* __restrict__ h3T,
                                                const float* __restrict__ W4,
                                                const float* __restrict__ gS3,
                                                const float* __restrict__ gQ3,
                                                const float* __restrict__ g3,
                                                const float* __restrict__ be3,
                                                const float* __restrict__ b4,
                                                float* __restrict__ out) {
    __shared__ __align__(16) char smem[37632];
    float* wS = (float*)smem;            // [64]
    float* sS = (float*)(smem + 256);    // [64]
    float* tS = (float*)(smem + 512);    // [64]
    unsigned short* sL = (unsigned short*)(smem + 768);  // [256][72]
    int tid = threadIdx.x;
    int i = blockIdx.x, b = blockIdx.y;
    if (tid < 64) {
        float su = 0.f, qu = 0.f;
        #pragma unroll
        for (int k = 0; k < 8; ++k) { su += gS3[k * 64 + tid]; qu += gQ3[k * 64 + tid]; }
        float mean = su * (1.f / 262144.f);
        float var = qu * (1.f / 262144.f) - mean * mean;
        float sc = g3[tid] * rsqrtf(var + EPS);
        wS[tid] = W4[tid];
        sS[tid] = sc;
        tS[tid] = be3[tid] - mean * sc;
    }
    const unsigned short* src = h3T + ((size_t)(b * 256 + i)) * 256 * 64;
    #pragma unroll
    for (int e = 0; e < 8; ++e) {
        int f = tid + 256 * e;
        uint4 v = *(const uint4*)(src + f * 8);
        *(uint4*)(sL + (f >> 3) * 72 + (f & 7) * 8) = v;
    }
    __syncthreads();
    float acc = 0.f;
    #pragma unroll
    for (int e = 0; e < 8; ++e) {
        uint4 v = *(const uint4*)(sL + tid * 72 + e * 8);
        unsigned int w[4] = {v.x, v.y, v.z, v.w};
        #pragma unroll
        for (int k = 0; k < 4; ++k) {
            int c = e * 8 + 2 * k;
            float f0 = bfu2f(w[k] & 0xffffu);
            float f1 = bfu2f(w[k] >> 16);
            acc += wS[c] * fmaxf(fmaf(f0, sS[c], tS[c]), 0.f);
            acc += wS[c + 1] * fmaxf(fmaf(f1, sS[c + 1], tS[c + 1]), 0.f);
        }
    }
    out[((size_t)(b * 256 + i)) * 256 + tid] = acc + b4[0];
}

extern "C" void kernel_launch(void* const* d_in, const int* in_sizes, int n_in,
                              void* d_out, int out_size, void* d_ws, size_t ws_size,
                              hipStream_t stream) {
    const float* feats = (const float*)d_in[0];
    const float* W1  = (const float*)d_in[1];
    const float* g1  = (const float*)d_in[3];
    const float* be1 = (const float*)d_in[4];
    const float* W2  = (const float*)d_in[5];
    const float* g2  = (const float*)d_in[7];
    const float* be2 = (const float*)d_in[8];
    const float* W3  = (const float*)d_in[9];
    const float* g3  = (const float*)d_in[11];
    const float* be3 = (const float*)d_in[12];
    const float* W4  = (const float*)d_in[13];
    const float* b4  = (const float*)d_in[14];

    char* ws = (char*)d_ws;
    float* fT   = (float*)(ws + OFF_FT);
    float* W1T  = (float*)(ws + OFF_W1T);
    unsigned short* W2b = (unsigned short*)(ws + OFF_W2B);
    unsigned short* W3b = (unsigned short*)(ws + OFF_W3B);
    float* abT  = (float*)(ws + OFF_ABT);
    float* s1   = (float*)(ws + OFF_S1);
    float* t1   = (float*)(ws + OFF_T1);
    float* gS2  = (float*)(ws + OFF_ST2);
    float* gQ2  = (float*)(ws + OFF_ST2 + 4096);
    float* gS3  = (float*)(ws + OFF_ST2 + 8192);
    float* gQ3  = (float*)(ws + OFF_ST2 + 10240);
    unsigned int* counter = (unsigned int*)(ws + OFF_ST2 + 12288);
    float2* part = (float2*)(ws + OFF_P1);
    unsigned short* h2T = (unsigned short*)(ws + OFF_H2T);
    unsigned short* h3T = (unsigned short*)(ws + OFF_H3T);
    float* out = (float*)d_out;

    k0kt<<<800, 256, 0, stream>>>(feats, W1, W2, W3, fT, W1T, W2b, W3b, (float*)(ws + OFF_ST2));
    k1_gemm<<<dim3(16, 16), 256, 0, stream>>>(W1T, fT, abT, part, g1, be1, s1, t1, counter);
    k2_mfma<<<dim3(256, 4), 256, 0, stream>>>(abT, W2b, s1, t1, h2T, gS2, gQ2);
    k3_mfma<<<dim3(256, 4), 256, 0, stream>>>(h2T, W3b, gS2, gQ2, g2, be2, h3T, gS3, gQ3);
    k4_final<<<dim3(256, 4), 256, 0, stream>>>(h3T, W4, gS3, gQ3, g3, be3, b4, out);
}

// Round 13
// 220.293 us; speedup vs baseline: 1.2874x; 1.2874x over previous
//
#include <hip/hip_runtime.h>
#include <hip/hip_bf16.h>

#define EPS 1e-5f

typedef __attribute__((ext_vector_type(8))) short bf16x8;
typedef __attribute__((ext_vector_type(4))) float f32x4;

// ---------------- workspace layout (bytes) ----------------
static constexpr size_t OFF_FT    = 0;             // fT[b][c][n] f32 (1 MB)
static constexpr size_t OFF_W1T   = 1048576;       // W1T[c][o512] f32 (512 KB)
static constexpr size_t OFF_W2B   = 1572864;       // W2 bf16 [128][256] (64 KB)
static constexpr size_t OFF_W3B   = 1638400;       // W3 bf16 [64][128] (16 KB)
static constexpr size_t OFF_S1    = 1654784;       // s1[256]
static constexpr size_t OFF_T1    = 1655808;       // t1[256]
static constexpr size_t OFF_ST2   = 1660928;       // gS2[8][128],gQ2[8][128],gS3[8][64],gQ3[8][64],counter
static constexpr size_t OFF_ABT   = 1703936;       // abT[b][n][o512] f32 (2 MB)
static constexpr size_t OFF_H2T   = 4194304;       // h2T bf16 (64 MB); k1 partials overlap (dead before k2)
static constexpr size_t OFF_P1    = OFF_H2T;       // part float2[16][512]
static constexpr size_t OFF_H3T   = 71303168;      // h3T bf16 (32 MB)

static __device__ inline float bfu2f(unsigned int u16) {
    return __uint_as_float(u16 << 16);
}
static __device__ inline unsigned short f2bfu(float f) {
    unsigned int u = __float_as_uint(f);
    unsigned int r = u + 0x7fffu + ((u >> 16) & 1u);   // RNE
    return (unsigned short)(r >> 16);
}
static __device__ inline unsigned int pkbf(float lo, float hi) {
    __hip_bfloat162 p = __float22bfloat162_rn(make_float2(lo, hi));   // v_cvt_pk_bf16_f32
    return *reinterpret_cast<unsigned int*>(&p);
}

// relu(bn(fv)) for 4 f32 lanes -> 4 packed bf16
static __device__ __forceinline__ uint2 bnpk4(float4 fv, const float* aa, const float* ss, int c) {
    float4 a4 = *(const float4*)(aa + c);
    float4 s4 = *(const float4*)(ss + c);
    float r0 = fmaxf(fmaf(fv.x, s4.x, a4.x), 0.f);
    float r1 = fmaxf(fmaf(fv.y, s4.y, a4.y), 0.f);
    float r2 = fmaxf(fmaf(fv.z, s4.z, a4.z), 0.f);
    float r3 = fmaxf(fmaf(fv.w, s4.w, a4.w), 0.f);
    return make_uint2(pkbf(r0, r1), pkbf(r2, r3));
}
// same but input = 4 bf16 packed in uint2
static __device__ __forceinline__ uint2 bn2pk4(uint2 v, const float* ss, const float* tt, int c) {
    float4 s4 = *(const float4*)(ss + c);
    float4 t4 = *(const float4*)(tt + c);
    float r0 = fmaxf(fmaf(bfu2f(v.x & 0xffffu), s4.x, t4.x), 0.f);
    float r1 = fmaxf(fmaf(bfu2f(v.x >> 16),     s4.y, t4.y), 0.f);
    float r2 = fmaxf(fmaf(bfu2f(v.y & 0xffffu), s4.z, t4.z), 0.f);
    float r3 = fmaxf(fmaf(bfu2f(v.y >> 16),     s4.w, t4.w), 0.f);
    return make_uint2(pkbf(r0, r1), pkbf(r2, r3));
}

// ---------------- K0KT: pair-mean transpose + weight prep + stats zeroing (800 blocks) ------
__global__ __launch_bounds__(256) void k0kt(const float* __restrict__ feats,
                                            const float* __restrict__ W1,
                                            const float* __restrict__ W2,
                                            const float* __restrict__ W3,
                                            float* __restrict__ fT, float* __restrict__ W1T,
                                            unsigned short* __restrict__ W2b,
                                            unsigned short* __restrict__ W3b,
                                            float* __restrict__ statsZero) {
    int bx = blockIdx.x, tid = threadIdx.x;
    if (bx < 128) {
        __shared__ float s[32][65];
        int b = bx >> 5, nt = (bx >> 2) & 7, ct = bx & 3;
        int n0 = nt * 32, c0 = ct * 64;
        const float* fb = feats + (size_t)b * 513 * 256;
        #pragma unroll
        for (int k = 0; k < 8; ++k) {
            int idx = tid + k * 256;
            int n = idx >> 6, c = idx & 63;
            const float* r = fb + (size_t)(1 + 2 * (n0 + n)) * 256 + c0 + c;
            s[n][c] = 0.5f * (r[0] + r[256]);
        }
        __syncthreads();
        #pragma unroll
        for (int k = 0; k < 8; ++k) {
            int idx = tid + k * 256;
            int c = idx >> 5, n = idx & 31;
            fT[((size_t)(b * 256) + c0 + c) * 256 + n0 + n] = s[n][c];
        }
    } else {
        if (bx == 128) {
            #pragma unroll
            for (int z = 0; z < 13; ++z) {
                int f = tid + z * 256;
                if (f < 3073) statsZero[f] = 0.f;   // gS2,gQ2,gS3,gQ3,counter
            }
        }
        int idx = (bx - 128) * 256 + tid;
        if (idx < 131072) {
            int c = idx >> 9, o = idx & 511;
            W1T[idx] = (o < 256) ? W1[(size_t)o * 512 + c] : W1[(size_t)(o - 256) * 512 + 256 + c];
        } else if (idx < 163840) {
            int j = idx - 131072;
            W2b[j] = f2bfu(W2[j]);
        } else if (idx < 172032) {
            int j = idx - 163840;
            W3b[j] = f2bfu(W3[j]);
        }
    }
}

// ---------------- K1: abT = W1T^T fT + BN1 partials; last block solves s1/t1 ----------------
__global__ __launch_bounds__(256) void k1_gemm(const float* __restrict__ W1T,
                                               const float* __restrict__ fT,
                                               float* __restrict__ abT,
                                               float2* __restrict__ part,
                                               const float* __restrict__ g1,
                                               const float* __restrict__ be1,
                                               float* __restrict__ s1,
                                               float* __restrict__ t1,
                                               unsigned int* __restrict__ counter) {
    __shared__ float sW[64][36];
    __shared__ float sF[64][68];
    int tid = threadIdx.x;
    int bx = blockIdx.x;
    int b = bx >> 2, n0 = (bx & 3) * 64;
    int o0 = blockIdx.y * 32;
    int og = tid >> 4, jq = tid & 15;
    float acc[2][4] = {};
    for (int c0 = 0; c0 < 256; c0 += 64) {
        #pragma unroll
        for (int k = 0; k < 8; ++k) {
            int idx = tid + k * 256;
            int c = idx >> 5, o = idx & 31;
            sW[c][o] = W1T[(size_t)(c0 + c) * 512 + o0 + o];
        }
        #pragma unroll
        for (int k = 0; k < 16; ++k) {
            int idx = tid + k * 256;
            int c = idx >> 6, n = idx & 63;
            sF[c][n] = fT[((size_t)(b * 256) + c0 + c) * 256 + n0 + n];
        }
        __syncthreads();
        #pragma unroll 8
        for (int c = 0; c < 64; ++c) {
            float4 rv = *(const float4*)&sF[c][jq * 4];
            float2 wv = *(const float2*)&sW[c][og * 2];
            float rr[4] = {rv.x, rv.y, rv.z, rv.w};
            #pragma unroll
            for (int w = 0; w < 4; ++w) {
                acc[0][w] = fmaf(wv.x, rr[w], acc[0][w]);
                acc[1][w] = fmaf(wv.y, rr[w], acc[1][w]);
            }
        }
        __syncthreads();
    }
    #pragma unroll
    for (int w = 0; w < 4; ++w) {
        int n = n0 + jq * 4 + w;
        *(float2*)&abT[((size_t)(b * 256) + n) * 512 + o0 + og * 2] =
            make_float2(acc[0][w], acc[1][w]);
    }
    #pragma unroll
    for (int m = 0; m < 2; ++m) {
        float s = 0.f, q = 0.f;
        #pragma unroll
        for (int w = 0; w < 4; ++w) { float v = acc[m][w]; s += v; q += v * v; }
        #pragma unroll
        for (int off = 8; off; off >>= 1) { s += __shfl_down(s, off); q += __shfl_down(q, off); }
        if (jq == 0) part[(size_t)bx * 512 + o0 + og * 2 + m] = make_float2(s, q);
    }
    // ticket: last block of 256 solves BN1 params
    __threadfence();
    __shared__ unsigned int lastFlag;
    if (tid == 0) lastFlag = (atomicAdd(counter, 1u) == 255u) ? 1u : 0u;
    __syncthreads();
    if (lastFlag) {
        int o = tid;   // 0..255
        float msum = 0.f, e2sum = 0.f;
        #pragma unroll
        for (int bb = 0; bb < 4; ++bb) {
            float Sa = 0.f, Qa = 0.f, Sb = 0.f, Qb = 0.f;
            #pragma unroll
            for (int nt = 0; nt < 4; ++nt) {
                float2 pa = part[(size_t)(bb * 4 + nt) * 512 + o];
                float2 pb = part[(size_t)(bb * 4 + nt) * 512 + 256 + o];
                Sa += pa.x; Qa += pa.y; Sb += pb.x; Qb += pb.y;
            }
            float ma = Sa * (1.f / 256.f), mb = Sb * (1.f / 256.f);
            msum += ma + mb;
            e2sum += Qa * (1.f / 256.f) + Qb * (1.f / 256.f) + 2.f * ma * mb;
        }
        float m = msum * 0.25f, e2 = e2sum * 0.25f;
        float var = e2 - m * m;
        float s = g1[o] * rsqrtf(var + EPS);
        s1[o] = s;
        t1[o] = be1[o] - m * s;
    }
}

// ---------------- K2: h2T = W2 @ relu(bn1(a_i + bp_j)) -- R4 structure, AGPR-safe stats -----
// grid (2 jt, 256 i, 4 b); 4 waves 2x2; tile 128o x 128j; K=256, BK=32, LDS staging.
// BN2 block-stats computed by column-reading the bf16 sT tile (no shfl on acc -> acc stays AGPR).
__global__ __launch_bounds__(256) void k2_mfma(const float* __restrict__ abT,
                                               const unsigned short* __restrict__ W2b,
                                               const float* __restrict__ s1,
                                               const float* __restrict__ t1,
                                               unsigned short* __restrict__ h2T,
                                               float* __restrict__ gS2,
                                               float* __restrict__ gQ2) {
    __shared__ __align__(16) char smem[35840];
    float* aaS = (float*)smem;                                    // [256]
    float* ssS = (float*)(smem + 1024);                           // [256]
    unsigned short* sW = (unsigned short*)(smem + 2048);          // [128][40]
    unsigned short* sB = (unsigned short*)(smem + 12288);         // [128][40]
    unsigned short* sT = (unsigned short*)smem;                   // [128][136] epilogue overlap
    float* sS = (float*)(smem + 34816);                           // [128]
    float* sQ = (float*)(smem + 35328);                           // [128]

    int tid = threadIdx.x;
    int j0 = blockIdx.x * 128, i = blockIdx.y, b = blockIdx.z;

    {
        float av = abT[((size_t)(b * 256 + i)) * 512 + tid];
        float s = s1[tid];
        aaS[tid] = fmaf(av, s, t1[tid]);
        ssS[tid] = s;
    }
    if (tid < 128) { sS[tid] = 0.f; sQ[tid] = 0.f; }
    __syncthreads();

    int lane = tid & 63, wv = tid >> 6;
    int wr = wv >> 1, wc = wv & 1;
    int lo = lane & 15, khi = lane >> 4;
    int jrow = tid >> 1, half = tid & 1;

    const float* bpRow = abT + ((size_t)(b * 256 + j0 + jrow)) * 512 + 256 + half * 16;
    const unsigned short* wRow = W2b + jrow * 256 + half * 16;

    f32x4 acc[4][4] = {};

    for (int c0 = 0; c0 < 256; c0 += 32) {
        // stage sW[o=jrow][c-chunk]
        {
            uint4 v0 = *(const uint4*)(wRow + c0);
            uint4 v1 = *(const uint4*)(wRow + c0 + 8);
            uint4* dst = (uint4*)(sW + jrow * 40 + half * 16);
            dst[0] = v0; dst[1] = v1;
        }
        // stage sB[j=jrow][c-chunk] = relu(bn1) bf16
        {
            float4 f0 = *(const float4*)(bpRow + c0);
            float4 f1 = *(const float4*)(bpRow + c0 + 4);
            float4 f2 = *(const float4*)(bpRow + c0 + 8);
            float4 f3 = *(const float4*)(bpRow + c0 + 12);
            int cb = c0 + half * 16;
            uint2 p0 = bnpk4(f0, aaS, ssS, cb);
            uint2 p1 = bnpk4(f1, aaS, ssS, cb + 4);
            uint2 p2 = bnpk4(f2, aaS, ssS, cb + 8);
            uint2 p3 = bnpk4(f3, aaS, ssS, cb + 12);
            uint4* dst = (uint4*)(sB + jrow * 40 + half * 16);
            dst[0] = make_uint4(p0.x, p0.y, p1.x, p1.y);
            dst[1] = make_uint4(p2.x, p2.y, p3.x, p3.y);
        }
        __syncthreads();
        const unsigned short* aB = sW + (wr * 64 + lo) * 40 + khi * 8;
        const unsigned short* bB = sB + (wc * 64 + lo) * 40 + khi * 8;
        bf16x8 af[4], bfr[4];
        #pragma unroll
        for (int fm = 0; fm < 4; ++fm) af[fm] = *(const bf16x8*)(aB + fm * 16 * 40);
        #pragma unroll
        for (int fn = 0; fn < 4; ++fn) bfr[fn] = *(const bf16x8*)(bB + fn * 16 * 40);
        #pragma unroll
        for (int fm = 0; fm < 4; ++fm)
            #pragma unroll
            for (int fn = 0; fn < 4; ++fn)
                acc[fm][fn] = __builtin_amdgcn_mfma_f32_16x16x32_bf16(af[fm], bfr[fn], acc[fm][fn], 0, 0, 0);
        __syncthreads();
    }

    // epilogue: LDS transpose to channel-last rows (single round, stride 136)
    #pragma unroll
    for (int fm = 0; fm < 4; ++fm)
        #pragma unroll
        for (int fn = 0; fn < 4; ++fn) {
            int oq = wr * 64 + fm * 16 + khi * 4;
            int j  = wc * 64 + fn * 16 + lo;
            *(uint2*)(sT + j * 136 + oq) =
                make_uint2(pkbf(acc[fm][fn][0], acc[fm][fn][1]),
                           pkbf(acc[fm][fn][2], acc[fm][fn][3]));
        }
    __syncthreads();
    {
        size_t gbase = (((size_t)(b * 256 + i)) * 256 + j0 + jrow) * 128 + half * 64;
        #pragma unroll
        for (int e = 0; e < 8; ++e) {
            uint4 v = *(const uint4*)(sT + jrow * 136 + half * 64 + e * 8);
            *(uint4*)(h2T + gbase + e * 8) = v;
        }
    }
    // BN2 block-stats: column-read of sT (bf16-rounded h2). 2-way bank aliasing = free.
    {
        int o = tid & 127, p = tid >> 7;
        const unsigned short* col = sT + (p * 64) * 136 + o;
        float s = 0.f, q = 0.f;
        for (int j = 0; j < 64; ++j) {
            float v = bfu2f(col[j * 136]);
            s += v; q += v * v;
        }
        atomicAdd(&sS[o], s);
        atomicAdd(&sQ[o], q);
    }
    __syncthreads();
    if (tid < 128) {
        int slot = (i & 7) * 128;
        atomicAdd(&gS2[slot + tid], sS[tid]);
        atomicAdd(&gQ2[slot + tid], sQ[tid]);
    }
}

// ---------------- K3: h3T = W3 @ relu(bn2(h2T)) -- inline bn2 params, AGPR-safe stats -------
// grid (256 i, 4 b); 4 waves 1x4; tile 64o x 256j; K=128, BK=32, LDS staging.
__global__ __launch_bounds__(256) void k3_mfma(const unsigned short* __restrict__ h2T,
                                               const unsigned short* __restrict__ W3b,
                                               const float* __restrict__ gS2,
                                               const float* __restrict__ gQ2,
                                               const float* __restrict__ g2,
                                               const float* __restrict__ be2,
                                               unsigned short* __restrict__ h3T,
                                               float* __restrict__ gS3,
                                               float* __restrict__ gQ3) {
    __shared__ __align__(16) char smem[39424];
    float* s2S = (float*)smem;                                    // [128]
    float* t2S = (float*)(smem + 512);                            // [128]
    unsigned short* sW3 = (unsigned short*)(smem + 1024);         // [64][136] full K
    unsigned short* sB  = (unsigned short*)(smem + 18432);        // [256][40] chunk
    float* sS = (float*)(smem + 38912);                           // [64]
    float* sQ = (float*)(smem + 39168);                           // [64]
    unsigned short* sT  = (unsigned short*)(smem + 1024);         // [256][72] epilogue overlap

    int tid = threadIdx.x;
    int i = blockIdx.x, b = blockIdx.y;
    if (tid < 128) {                       // inline BN2 param solve
        float su = 0.f, qu = 0.f;
        #pragma unroll
        for (int k = 0; k < 8; ++k) { su += gS2[k * 128 + tid]; qu += gQ2[k * 128 + tid]; }
        float mean = su * (1.f / 262144.f);
        float var = qu * (1.f / 262144.f) - mean * mean;
        float sc = g2[tid] * rsqrtf(var + EPS);
        s2S[tid] = sc;
        t2S[tid] = be2[tid] - mean * sc;
    }
    if (tid < 64) { sS[tid] = 0.f; sQ[tid] = 0.f; }
    {
        int o = tid >> 2, qd = tid & 3;
        #pragma unroll
        for (int e = 0; e < 4; ++e) {
            uint4 v = *(const uint4*)(W3b + o * 128 + qd * 32 + e * 8);
            *(uint4*)(sW3 + o * 136 + qd * 32 + e * 8) = v;
        }
    }
    __syncthreads();

    int lane = tid & 63, wv = tid >> 6;
    int lo = lane & 15, khi = lane >> 4;

    f32x4 acc[4][4] = {};
    const unsigned short* src = h2T + (((size_t)(b * 256 + i)) * 256 + tid) * 128;

    for (int c0 = 0; c0 < 128; c0 += 32) {
        #pragma unroll
        for (int e = 0; e < 4; ++e) {
            uint4 v = *(const uint4*)(src + c0 + e * 8);
            int c = c0 + e * 8;
            uint2 pa = bn2pk4(make_uint2(v.x, v.y), s2S, t2S, c);
            uint2 pb = bn2pk4(make_uint2(v.z, v.w), s2S, t2S, c + 4);
            *(uint4*)(sB + tid * 40 + e * 8) = make_uint4(pa.x, pa.y, pb.x, pb.y);
        }
        __syncthreads();
        bf16x8 af[4], bfr[4];
        #pragma unroll
        for (int fm = 0; fm < 4; ++fm)
            af[fm] = *(const bf16x8*)(sW3 + (fm * 16 + lo) * 136 + c0 + khi * 8);
        #pragma unroll
        for (int fn = 0; fn < 4; ++fn)
            bfr[fn] = *(const bf16x8*)(sB + (wv * 64 + fn * 16 + lo) * 40 + khi * 8);
        #pragma unroll
        for (int fm = 0; fm < 4; ++fm)
            #pragma unroll
            for (int fn = 0; fn < 4; ++fn)
                acc[fm][fn] = __builtin_amdgcn_mfma_f32_16x16x32_bf16(af[fm], bfr[fn], acc[fm][fn], 0, 0, 0);
        __syncthreads();
    }

    // epilogue: transpose to channel-last
    #pragma unroll
    for (int fm = 0; fm < 4; ++fm)
        #pragma unroll
        for (int fn = 0; fn < 4; ++fn) {
            int oq = fm * 16 + khi * 4;
            int j  = wv * 64 + fn * 16 + lo;
            *(uint2*)(sT + j * 72 + oq) =
                make_uint2(pkbf(acc[fm][fn][0], acc[fm][fn][1]),
                           pkbf(acc[fm][fn][2], acc[fm][fn][3]));
        }
    __syncthreads();
    {
        size_t gbase = (((size_t)(b * 256 + i)) * 256 + tid) * 64;
        #pragma unroll
        for (int e = 0; e < 8; ++e) {
            uint4 v = *(const uint4*)(sT + tid * 72 + e * 8);
            *(uint4*)(h3T + gbase + e * 8) = v;
        }
    }
    // BN3 block-stats: column-read of sT (bf16-rounded h3)
    {
        int o = tid & 63, p = tid >> 6;
        const unsigned short* col = sT + (p * 64) * 72 + o;
        float s = 0.f, q = 0.f;
        for (int j = 0; j < 64; ++j) {
            float v = bfu2f(col[j * 72]);
            s += v; q += v * v;
        }
        atomicAdd(&sS[o], s);
        atomicAdd(&sQ[o], q);
    }
    __syncthreads();
    if (tid < 64) {
        int slot = (i & 7) * 64;
        atomicAdd(&gS3[slot + tid], sS[tid]);
        atomicAdd(&gQ3[slot + tid], sQ[tid]);
    }
}

// ---------------- K4: out = W4 @ relu(bn3(h3T)) + b4, inline bn3 params ----------------
__global__ __launch_bounds__(256) void k4_final(const unsigned short* __restrict__ h3T,
                                                const float* __restrict__ W4,
                                                const float* __restrict__ gS3,
                                                const float* __restrict__ gQ3,
                                                const float* __restrict__ g3,
                                                const float* __restrict__ be3,
                                                const float* __restrict__ b4,
                                                float* __restrict__ out) {
    __shared__ __align__(16) char smem[37632];
    float* wS = (float*)smem;            // [64]
    float* sS = (float*)(smem + 256);    // [64]
    float* tS = (float*)(smem + 512);    // [64]
    unsigned short* sL = (unsigned short*)(smem + 768);  // [256][72]
    int tid = threadIdx.x;
    int i = blockIdx.x, b = blockIdx.y;
    if (tid < 64) {
        float su = 0.f, qu = 0.f;
        #pragma unroll
        for (int k = 0; k < 8; ++k) { su += gS3[k * 64 + tid]; qu += gQ3[k * 64 + tid]; }
        float mean = su * (1.f / 262144.f);
        float var = qu * (1.f / 262144.f) - mean * mean;
        float sc = g3[tid] * rsqrtf(var + EPS);
        wS[tid] = W4[tid];
        sS[tid] = sc;
        tS[tid] = be3[tid] - mean * sc;
    }
    const unsigned short* src = h3T + ((size_t)(b * 256 + i)) * 256 * 64;
    #pragma unroll
    for (int e = 0; e < 8; ++e) {
        int f = tid + 256 * e;
        uint4 v = *(const uint4*)(src + f * 8);
        *(uint4*)(sL + (f >> 3) * 72 + (f & 7) * 8) = v;
    }
    __syncthreads();
    float acc = 0.f;
    #pragma unroll
    for (int e = 0; e < 8; ++e) {
        uint4 v = *(const uint4*)(sL + tid * 72 + e * 8);
        unsigned int w[4] = {v.x, v.y, v.z, v.w};
        #pragma unroll
        for (int k = 0; k < 4; ++k) {
            int c = e * 8 + 2 * k;
            float f0 = bfu2f(w[k] & 0xffffu);
            float f1 = bfu2f(w[k] >> 16);
            acc += wS[c] * fmaxf(fmaf(f0, sS[c], tS[c]), 0.f);
            acc += wS[c + 1] * fmaxf(fmaf(f1, sS[c + 1], tS[c + 1]), 0.f);
        }
    }
    out[((size_t)(b * 256 + i)) * 256 + tid] = acc + b4[0];
}

extern "C" void kernel_launch(void* const* d_in, const int* in_sizes, int n_in,
                              void* d_out, int out_size, void* d_ws, size_t ws_size,
                              hipStream_t stream) {
    const float* feats = (const float*)d_in[0];
    const float* W1  = (const float*)d_in[1];
    const float* g1  = (const float*)d_in[3];
    const float* be1 = (const float*)d_in[4];
    const float* W2  = (const float*)d_in[5];
    const float* g2  = (const float*)d_in[7];
    const float* be2 = (const float*)d_in[8];
    const float* W3  = (const float*)d_in[9];
    const float* g3  = (const float*)d_in[11];
    const float* be3 = (const float*)d_in[12];
    const float* W4  = (const float*)d_in[13];
    const float* b4  = (const float*)d_in[14];

    char* ws = (char*)d_ws;
    float* fT   = (float*)(ws + OFF_FT);
    float* W1T  = (float*)(ws + OFF_W1T);
    unsigned short* W2b = (unsigned short*)(ws + OFF_W2B);
    unsigned short* W3b = (unsigned short*)(ws + OFF_W3B);
    float* abT  = (float*)(ws + OFF_ABT);
    float* s1   = (float*)(ws + OFF_S1);
    float* t1   = (float*)(ws + OFF_T1);
    float* gS2  = (float*)(ws + OFF_ST2);
    float* gQ2  = (float*)(ws + OFF_ST2 + 4096);
    float* gS3  = (float*)(ws + OFF_ST2 + 8192);
    float* gQ3  = (float*)(ws + OFF_ST2 + 10240);
    unsigned int* counter = (unsigned int*)(ws + OFF_ST2 + 12288);
    float2* part = (float2*)(ws + OFF_P1);
    unsigned short* h2T = (unsigned short*)(ws + OFF_H2T);
    unsigned short* h3T = (unsigned short*)(ws + OFF_H3T);
    float* out = (float*)d_out;

    k0kt<<<800, 256, 0, stream>>>(feats, W1, W2, W3, fT, W1T, W2b, W3b, (float*)(ws + OFF_ST2));
    k1_gemm<<<dim3(16, 16), 256, 0, stream>>>(W1T, fT, abT, part, g1, be1, s1, t1, counter);
    k2_mfma<<<dim3(2, 256, 4), 256, 0, stream>>>(abT, W2b, s1, t1, h2T, gS2, gQ2);
    k3_mfma<<<dim3(256, 4), 256, 0, stream>>>(h2T, W3b, gS2, gQ2, g2, be2, h3T, gS3, gQ3);
    k4_final<<<dim3(256, 4), 256, 0, stream>>>(h3T, W4, gS3, gQ3, g3, be3, b4, out);
}